// Round 1
// 59.857 us; speedup vs baseline: 1.0009x; 1.0009x over previous
//
#include <hip/hip_runtime.h>

// Problem constants (from reference): B=32, N=2048, OUT=100
#define BATCH  32
#define NDIM   2048
#define NOUT   100
#define OG     8                  // outputs per block (two float4 column-chunks)
#define NOG    13                 // ceil(NOUT / OG)
#define BLOCK  256
#define NCHUNK (BLOCK / 2)        // 128 j-chunks (o4 = t&1, ch = t>>1)
#define CHUNK  (NDIM / NCHUNK)    // 16 j per chunk

// out[b,o] = sum_j rem[b,j] * W[j,o]
// rem[b,j] = (q[b,j] - (N*c[b,j] + S[b]))^2,  c = (int)q, S[b] = sum_j c[b,j]
//
// Single dispatch, no atomics, no memset. Each block owns (batch b, 8 output
// columns). Phase 2 is vectorized along the output dim: W columns 8g..8g+7
// split into two 16B-aligned float4s (byte offset 32g/+16, row stride 400B),
// so each thread issues 16 global_load_dwordx4 instead of 64 scalar loads.
__global__ __launch_bounds__(BLOCK)
void fused_model_kernel(const float* __restrict__ q,
                        const float* __restrict__ W,
                        float* __restrict__ out)
{
    const int g = blockIdx.x;   // output-group index [0,NOG)
    const int b = blockIdx.y;   // batch row
    const int t = threadIdx.x;

    __shared__ __align__(16) float rem_lds[NDIM];   // 8 KB: full row's rem
    __shared__ int   wave_sum[BLOCK / 64];
    __shared__ float wred[BLOCK / 64][OG];

    // ---- Phase 1: float4 row load (coalesced); exact int row-sum S ----
    const float4* qrow4 = (const float4*)(q + b * NDIM);
    const float4 v0 = qrow4[t];          // elements 4t .. 4t+3
    const float4 v1 = qrow4[BLOCK + t];  // elements 1024+4t ..

    const int c0x = (int)v0.x, c0y = (int)v0.y, c0z = (int)v0.z, c0w = (int)v0.w;
    const int c1x = (int)v1.x, c1y = (int)v1.y, c1z = (int)v1.z, c1w = (int)v1.w;
    int csum = c0x + c0y + c0z + c0w + c1x + c1y + c1z + c1w;

    #pragma unroll
    for (int m = 32; m > 0; m >>= 1) csum += __shfl_xor(csum, m, 64);
    if ((t & 63) == 0) wave_sum[t >> 6] = csum;
    __syncthreads();
    // Every thread folds the 4 wave partials itself: saves one barrier.
    const int S = wave_sum[0] + wave_sum[1] + wave_sum[2] + wave_sum[3];

    // ---- rem for the 8 elements this thread already holds (exact int math,
    //      |N*c + S| << 2^24 so the float conversion is exact) ----
    {
        const int j0 = 4 * t, j1 = 4 * BLOCK + 4 * t;
        float d;
        d = v0.x - (float)(NDIM * c0x + S); rem_lds[j0 + 0] = d * d;
        d = v0.y - (float)(NDIM * c0y + S); rem_lds[j0 + 1] = d * d;
        d = v0.z - (float)(NDIM * c0z + S); rem_lds[j0 + 2] = d * d;
        d = v0.w - (float)(NDIM * c0w + S); rem_lds[j0 + 3] = d * d;
        d = v1.x - (float)(NDIM * c1x + S); rem_lds[j1 + 0] = d * d;
        d = v1.y - (float)(NDIM * c1y + S); rem_lds[j1 + 1] = d * d;
        d = v1.z - (float)(NDIM * c1z + S); rem_lds[j1 + 2] = d * d;
        d = v1.w - (float)(NDIM * c1w + S); rem_lds[j1 + 3] = d * d;
    }
    __syncthreads();

    // ---- Phase 2: 2 float4 column-chunks x 128 j-chunks of 16 j each ----
    const int o4   = t & 1;               // which float4 of the 8-col group
    const int ch   = t >> 1;              // j-chunk [0,128)
    const int jb   = ch * CHUNK;
    const int colb = g * OG + 4 * o4;     // first column of this float4

    float ax = 0.f, ay = 0.f, az = 0.f, aw = 0.f;
    if (colb < NOUT) {                    // false only for g==12, o4==1
        const float4* Wp = (const float4*)(W + (size_t)jb * NOUT + colb);
        const float4* rp = (const float4*)(rem_lds + jb);

        float r[CHUNK];
        #pragma unroll
        for (int k = 0; k < CHUNK / 4; ++k) {   // 4x ds_read_b128
            const float4 rv = rp[k];
            r[4 * k + 0] = rv.x; r[4 * k + 1] = rv.y;
            r[4 * k + 2] = rv.z; r[4 * k + 3] = rv.w;
        }
        #pragma unroll
        for (int j = 0; j < CHUNK; ++j) {       // 16x global_load_dwordx4
            const float4 wv = Wp[(size_t)j * (NOUT / 4)];
            ax += r[j] * wv.x;
            ay += r[j] * wv.y;
            az += r[j] * wv.z;
            aw += r[j] * wv.w;
        }
    }

    // Reduce over the 32 chunks within each wave: lane bits 1-5 (never mixes o4).
    #pragma unroll
    for (int m = 2; m <= 32; m <<= 1) {
        ax += __shfl_xor(ax, m, 64);
        ay += __shfl_xor(ay, m, 64);
        az += __shfl_xor(az, m, 64);
        aw += __shfl_xor(aw, m, 64);
    }
    if ((t & 63) < 2) {
        float* wr = wred[t >> 6];
        const int base = 4 * (t & 1);
        wr[base + 0] = ax; wr[base + 1] = ay;
        wr[base + 2] = az; wr[base + 3] = aw;
    }
    __syncthreads();

    // Combine the 4 waves; one plain store per output element.
    if (t < OG) {
        const int oc = g * OG + t;
        if (oc < NOUT)
            out[b * NOUT + oc] = wred[0][t] + wred[1][t] + wred[2][t] + wred[3][t];
    }
}

extern "C" void kernel_launch(void* const* d_in, const int* in_sizes, int n_in,
                              void* d_out, int out_size, void* d_ws, size_t ws_size,
                              hipStream_t stream) {
    const float* q = (const float*)d_in[0];   // [32, 2048] f32
    const float* W = (const float*)d_in[1];   // [2048, 100] f32
    float* out = (float*)d_out;               // [32, 100] f32

    dim3 grid(NOG, BATCH);                    // 13 x 32 = 416 blocks
    fused_model_kernel<<<grid, BLOCK, 0, stream>>>(q, W, out);
}